// Round 3
// baseline (414.129 us; speedup 1.0000x reference)
//
#include <hip/hip_runtime.h>

#define TSTEPS 500
#define NB 32
#define RS 1024
#define CD 5120
#define LT 400
#define NC 396
#define NEGF (-1e30f)
#define L2E 1.4426950408889634f
#define LN2f 0.6931471805599453f

// vmcnt-preserving barrier: drain LDS ops only, raw s_barrier, NO "memory"
// clobber anywhere (a memory clobber makes SIInsertWaitcnts emit vmcnt(0)
// and kills the global prefetch pipeline). sched_barrier(0) pins ordering.
#define BARRIER() do {                                   \
    __builtin_amdgcn_sched_barrier(0);                   \
    asm volatile("s_waitcnt lgkmcnt(0)");                \
    __builtin_amdgcn_s_barrier();                        \
    __builtin_amdgcn_sched_barrier(0);                   \
} while (0)

struct F10 { float2 a, b, c, d, e; };   // 2 states x 5 transition scores

__device__ __forceinline__ void ldm(const float* __restrict__ p, F10& M) {
    const float2* p2 = (const float2*)p;
    M.a = p2[0]; M.b = p2[1]; M.c = p2[2]; M.d = p2[3]; M.e = p2[4];
}

// One trellis step for states r0=2i, r1=2i+1 (log2 domain). Both share the
// parent quad {q, q+256, q+512, q+768}, q = i>>1. Alpha LDS traffic is
// volatile so it cannot be reordered across the raw s_barrier.
__device__ __forceinline__ void tstep(const F10& M, float (&ao)[2],
                                      const volatile float* ar,
                                      volatile float* aw, int i) {
    const int q = i >> 1;
    float p0 = ar[q], p1 = ar[q + 256], p2 = ar[q + 512], p3 = ar[q + 768];
    float r0, r1;
    {
        float t0 = fmaf(M.a.x, L2E, ao[0]);
        float t1 = fmaf(M.a.y, L2E, p0);
        float t2 = fmaf(M.b.x, L2E, p1);
        float t3 = fmaf(M.b.y, L2E, p2);
        float t4 = fmaf(M.c.x, L2E, p3);
        float mx = fmaxf(fmaxf(fmaxf(t0, t1), t2), fmaxf(t3, t4));
        float e = exp2f(t0-mx)+exp2f(t1-mx)+exp2f(t2-mx)+exp2f(t3-mx)+exp2f(t4-mx);
        r0 = mx + log2f(e);
    }
    {
        float t0 = fmaf(M.c.y, L2E, ao[1]);
        float t1 = fmaf(M.d.x, L2E, p0);
        float t2 = fmaf(M.d.y, L2E, p1);
        float t3 = fmaf(M.e.x, L2E, p2);
        float t4 = fmaf(M.e.y, L2E, p3);
        float mx = fmaxf(fmaxf(fmaxf(t0, t1), t2), fmaxf(t3, t4));
        float e = exp2f(t0-mx)+exp2f(t1-mx)+exp2f(t2-mx)+exp2f(t3-mx)+exp2f(t4-mx);
        r1 = mx + log2f(e);
    }
    ao[0] = r0; ao[1] = r1;
    aw[2*i]     = r0;
    aw[2*i + 1] = r1;
}

// ---------------- banded CTC (one wave per batch, no barriers) ----------------
__device__ __forceinline__ void ldc(const float* __restrict__ p,
                                    const int (&so)[7], const int (&mo)[7],
                                    float (&S)[7], float (&V)[7]) {
#pragma unroll
    for (int k = 0; k < 7; ++k) { S[k] = p[so[k]]; V[k] = p[mo[k]]; }
}

__device__ __forceinline__ void cstep(const float (&S)[7], const float (&V)[7],
                                      float (&ac)[7], int lane) {
    float prev = __shfl_up(ac[6], 1, 64);
    float nw[7];
#pragma unroll
    for (int k = 0; k < 7; ++k) {
        float left = k ? ac[k-1] : prev;
        float x = fmaf(S[k], L2E, ac[k]);
        float y = fmaf(V[k], L2E, left);
        if (k == 0) y = (lane == 0) ? NEGF : y;
        float m2 = fmaxf(x, y);
        float d  = fminf(x, y) - m2;
        nw[k] = m2 + log2f(1.0f + exp2f(d));
    }
#pragma unroll
    for (int k = 0; k < 7; ++k) ac[k] = nw[k];
}

extern "C" __global__ void __launch_bounds__(512, 1)
ctc_crf(const float* __restrict__ scores, const int* __restrict__ targets,
        const int* __restrict__ tlens, float* __restrict__ out)
{
    const int tid = threadIdx.x;
    const size_t STP = (size_t)NB * CD;

    if (blockIdx.x < NB) {
        // ======================= trellis logZ =======================
        const int b = blockIdx.x;
        __shared__ float a_tr[2][RS];
        __shared__ float red[8], red2[8];

        *(float2*)&a_tr[0][2*tid] = make_float2(0.f, 0.f);
        __syncthreads();

        volatile float* A0 = &a_tr[0][0];
        volatile float* A1 = &a_tr[1][0];

        const float* base = scores + (size_t)b*CD + (size_t)tid*10;
        const float* p0 = base;
        const float* p1 = base +   STP;
        const float* p2 = base + 2*STP;
        const float* p3 = base + 3*STP;
        const float* p4 = base + 4*STP;
        const float* p5 = base + 5*STP;
        const float* p6 = base + 6*STP;
        const float* p7 = base + 7*STP;

        F10 B0, B1, B2, B3, B4, B5, B6, B7;
        ldm(p0, B0); ldm(p1, B1); ldm(p2, B2); ldm(p3, B3);
        ldm(p4, B4); ldm(p5, B5); ldm(p6, B6); ldm(p7, B7);

        float ao[2] = {0.f, 0.f};

        for (int t = 0; t < 496; t += 8) {
            tstep(B0, ao, A0, A1, tid);
            if (t +  8 < TSTEPS) { p0 += 8*STP; ldm(p0, B0); }
            BARRIER();
            tstep(B1, ao, A1, A0, tid);
            if (t +  9 < TSTEPS) { p1 += 8*STP; ldm(p1, B1); }
            BARRIER();
            tstep(B2, ao, A0, A1, tid);
            if (t + 10 < TSTEPS) { p2 += 8*STP; ldm(p2, B2); }
            BARRIER();
            tstep(B3, ao, A1, A0, tid);
            if (t + 11 < TSTEPS) { p3 += 8*STP; ldm(p3, B3); }
            BARRIER();
            tstep(B4, ao, A0, A1, tid);
            if (t + 12 < TSTEPS) { p4 += 8*STP; ldm(p4, B4); }
            BARRIER();
            tstep(B5, ao, A1, A0, tid);
            if (t + 13 < TSTEPS) { p5 += 8*STP; ldm(p5, B5); }
            BARRIER();
            tstep(B6, ao, A0, A1, tid);
            if (t + 14 < TSTEPS) { p6 += 8*STP; ldm(p6, B6); }
            BARRIER();
            tstep(B7, ao, A1, A0, tid);
            if (t + 15 < TSTEPS) { p7 += 8*STP; ldm(p7, B7); }
            BARRIER();
        }
        // epilogue: steps 496..499 consume B0..B3 (already loaded)
        tstep(B0, ao, A0, A1, tid); BARRIER();
        tstep(B1, ao, A1, A0, tid); BARRIER();
        tstep(B2, ao, A0, A1, tid); BARRIER();
        tstep(B3, ao, A1, A0, tid);

        // Block-wide LSE over 1024 states (log2 domain).
        float m2 = fmaxf(ao[0], ao[1]);
#pragma unroll
        for (int off = 32; off >= 1; off >>= 1)
            m2 = fmaxf(m2, __shfl_xor(m2, off, 64));
        const int w = tid >> 6, ln = tid & 63;
        if (ln == 0) red[w] = m2;
        __syncthreads();
        float g = red[0];
#pragma unroll
        for (int i = 1; i < 8; ++i) g = fmaxf(g, red[i]);
        float e2 = exp2f(ao[0] - g) + exp2f(ao[1] - g);
#pragma unroll
        for (int off = 32; off >= 1; off >>= 1)
            e2 += __shfl_xor(e2, off, 64);
        if (ln == 0) red2[w] = e2;
        __syncthreads();
        if (tid == 0) {
            float tot = 0.f;
#pragma unroll
            for (int i = 0; i < 8; ++i) tot += red2[i];
            float logz_ln = LN2f * (g + log2f(tot));
            int tl = tlens[b];
            atomicAdd(out, logz_ln / ((float)tl * NB));
        }
    } else {
        // ======================= banded CTC logZ =======================
        if (tid >= 64) return;
        const int b = blockIdx.x - NB;
        const int lane = tid;

        int tloc[12];
#pragma unroll
        for (int j = 0; j < 12; ++j) {
            int gi = 7*lane - 1 + j;
            gi = gi < 0 ? 0 : (gi > LT-1 ? LT-1 : gi);
            int v = targets[b*LT + gi] - 1;
            tloc[j] = v < 0 ? 0 : v;
        }
        int so[7], mo[7];
#pragma unroll
        for (int k = 0; k < 7; ++k) {
            int gi = 7*lane + k;
            if (gi < NC) {
                int K = tloc[k+1];
                K = K*4 + tloc[k+2];
                K = K*4 + tloc[k+3];
                K = K*4 + tloc[k+4];
                K = K*4 + tloc[k+5];
                so[k] = K*5;
                mo[k] = (gi >= 1) ? (so[k] + tloc[k] + 1) : 0;
            } else { so[k] = 0; mo[k] = 0; }
        }

        float ac[7];
#pragma unroll
        for (int k = 0; k < 7; ++k) ac[k] = (7*lane + k == 0) ? 0.0f : NEGF;

        const float* q0 = scores + (size_t)b*CD;
        const float* q1 = q0 + STP;
        const float* q2 = q0 + 2*STP;
        const float* q3 = q0 + 3*STP;
        float S0[7], V0[7], S1[7], V1[7], S2[7], V2[7], S3[7], V3[7];
        ldc(q0, so, mo, S0, V0); ldc(q1, so, mo, S1, V1);
        ldc(q2, so, mo, S2, V2); ldc(q3, so, mo, S3, V3);

        for (int t = 0; t < TSTEPS; t += 4) {
            cstep(S0, V0, ac, lane);
            if (t+4 < TSTEPS) { q0 += 4*STP; ldc(q0, so, mo, S0, V0); }
            cstep(S1, V1, ac, lane);
            if (t+5 < TSTEPS) { q1 += 4*STP; ldc(q1, so, mo, S1, V1); }
            cstep(S2, V2, ac, lane);
            if (t+6 < TSTEPS) { q2 += 4*STP; ldc(q2, so, mo, S2, V2); }
            cstep(S3, V3, ac, lane);
            if (t+7 < TSTEPS) { q3 += 4*STP; ldc(q3, so, mo, S3, V3); }
        }

        int tl = tlens[b];
        int idx = tl - 5;                 // alphaT[lengths-1], lengths = tl+1-5
        int srcLane = idx / 7, slot = idx % 7;
        float v = ac[0];
#pragma unroll
        for (int k = 1; k < 7; ++k) v = (slot == k) ? ac[k] : v;
        float r = __shfl(v, srcLane, 64);
        if (lane == 0)
            atomicAdd(out, -LN2f * r / ((float)tl * NB));
    }
}

extern "C" void kernel_launch(void* const* d_in, const int* in_sizes, int n_in,
                              void* d_out, int out_size, void* d_ws, size_t ws_size,
                              hipStream_t stream) {
    const float* scores  = (const float*)d_in[0];
    const int*   targets = (const int*)d_in[1];
    const int*   tlens   = (const int*)d_in[2];
    float* out = (float*)d_out;

    hipMemsetAsync(out, 0, sizeof(float), stream);
    ctc_crf<<<2*NB, 512, 0, stream>>>(scores, targets, tlens, out);
}

// Round 4
// 201.190 us; speedup vs baseline: 2.0584x; 2.0584x over previous
//
#include <hip/hip_runtime.h>
#include <stdint.h>

#define TT 500
#define HT 250            // steps per direction
#define NB 32
#define RS 1024
#define CD 5120
#define LT 400
#define NC 396
#define NEGF (-1e30f)
#define L2E 1.4426950408889634f
#define LN2f 0.6931471805599453f

#define SLAB_F CD                       // floats per time-slab
#define NRING 5                         // LDS ring slots
#define SMEM_FLOATS (NRING*SLAB_F + 2*RS)
#define SMEM_BYTES  (SMEM_FLOATS*4)     // 110592 B

// workspace layout (floats)
#define WS_AT 0                         // [NB][RS] trellis alpha @ t=250
#define WS_BT (NB*RS)                   // [NB][RS] trellis beta  @ t=250
#define WS_AC (2*NB*RS)                 // [NB][NC] ctc alpha mid
#define WS_BC (2*NB*RS + NB*NC)         // [NB][NC] ctc beta mid

// One wave stages its contiguous 5 KB quarter of a 20 KB slab: 5 x 16B/lane.
__device__ __forceinline__ void stage5(const float* g, float* l, int lane) {
#pragma unroll
    for (int m = 0; m < 5; ++m) {
        __builtin_amdgcn_global_load_lds(
            (const __attribute__((address_space(1))) void*)(g + m*256 + lane*4),
            (__attribute__((address_space(3))) void*)(l + m*256),
            16, 0, 0);
    }
}

__device__ __forceinline__ float lse5(float t0, float t1, float t2, float t3, float t4) {
    float mx = fmaxf(fmaxf(fmaxf(t0,t1),t2), fmaxf(t3,t4));
    float e = exp2f(t0-mx)+exp2f(t1-mx)+exp2f(t2-mx)+exp2f(t3-mx)+exp2f(t4-mx);
    return mx + log2f(e);
}

#define PHASE_SYNC() do {                                  \
    __builtin_amdgcn_sched_barrier(0);                     \
    asm volatile("s_waitcnt vmcnt(15) lgkmcnt(0)");        \
    __builtin_amdgcn_s_barrier();                          \
    __builtin_amdgcn_sched_barrier(0);                     \
} while (0)

// ===================== trellis forward (250 steps) =====================
__device__ void trellis_fwd(const float* __restrict__ scores, float* __restrict__ ws,
                            int b, int tid, float* sm) {
    const int lane = tid & 63, w = tid >> 6;
    float* aping = sm + NRING*SLAB_F;
    float* apong = aping + RS;
    *(float4*)&aping[4*tid] = make_float4(0.f,0.f,0.f,0.f);
    __syncthreads();

    const size_t STP = (size_t)NB*CD;
    const float* gb = scores + (size_t)b*CD;
    const int woff = w*1280;
#pragma unroll
    for (int p = 0; p < 4; ++p)
        stage5(gb + (size_t)p*STP + woff, sm + p*SLAB_F + woff, lane);

    float ao[4] = {0.f,0.f,0.f,0.f};
    float* ar = aping; float* aw = apong;
    int t = 0;
    for (int it = 0; it < HT/NRING; ++it) {
#pragma unroll
        for (int k = 0; k < NRING; ++k) {
            PHASE_SYNC();
            int ts = t + 4; if (ts > HT-1) ts = HT-1;
            stage5(gb + (size_t)ts*STP + woff, sm + ((k+4)%NRING)*SLAB_F + woff, lane);
            const float4* S4 = (const float4*)(sm + k*SLAB_F + 20*tid);
            float4 r0=S4[0], r1=S4[1], r2=S4[2], r3=S4[3], r4=S4[4];
            float f[20] = {r0.x,r0.y,r0.z,r0.w, r1.x,r1.y,r1.z,r1.w,
                           r2.x,r2.y,r2.z,r2.w, r3.x,r3.y,r3.z,r3.w,
                           r4.x,r4.y,r4.z,r4.w};
            float p0 = ar[tid], p1 = ar[tid+256], p2 = ar[tid+512], p3 = ar[tid+768];
            float nw[4];
#pragma unroll
            for (int s = 0; s < 4; ++s) {
                nw[s] = lse5(fmaf(f[5*s+0],L2E,ao[s]), fmaf(f[5*s+1],L2E,p0),
                             fmaf(f[5*s+2],L2E,p1),   fmaf(f[5*s+3],L2E,p2),
                             fmaf(f[5*s+4],L2E,p3));
                ao[s] = nw[s];
            }
            *(float4*)&aw[4*tid] = make_float4(nw[0],nw[1],nw[2],nw[3]);
            float* tp_ = ar; ar = aw; aw = tp_;
            ++t;
        }
    }
    *(float4*)&ws[WS_AT + b*RS + 4*tid] = make_float4(ao[0],ao[1],ao[2],ao[3]);
}

// ===================== trellis backward (250 steps, t=499..250) =====================
// beta_t[p] = LSE( M[p,0]+beta'[p], M[4(p&255)+k, (p>>8)+1]+beta'[4(p&255)+k] )
__device__ void trellis_bwd(const float* __restrict__ scores, float* __restrict__ ws,
                            int b, int tid, float* sm) {
    const int lane = tid & 63, w = tid >> 6;
    float* bping = sm + NRING*SLAB_F;
    float* bpong = bping + RS;
    *(float4*)&bping[4*tid] = make_float4(0.f,0.f,0.f,0.f);  // beta_500 = 0
    __syncthreads();

    const size_t STP = (size_t)NB*CD;
    const float* gb = scores + (size_t)b*CD;
    const int woff = w*1280;
#pragma unroll
    for (int p = 0; p < 4; ++p)
        stage5(gb + (size_t)(TT-1-p)*STP + woff, sm + p*SLAB_F + woff, lane);

    float bo[4] = {0.f,0.f,0.f,0.f};     // own states tid+256j (beta_500 = 0)
    float* br = bping; float* bw = bpong;
    int pp = 0;
    for (int it = 0; it < HT/NRING; ++it) {
#pragma unroll
        for (int k = 0; k < NRING; ++k) {
            PHASE_SYNC();
            int ps = pp + 4; if (ps > HT-1) ps = HT-1;
            stage5(gb + (size_t)(TT-1-ps)*STP + woff, sm + ((k+4)%NRING)*SLAB_F + woff, lane);
            float* slab = sm + k*SLAB_F;
            const float4* S4 = (const float4*)(slab + 20*tid);
            float4 r0=S4[0], r1=S4[1], r2=S4[2], r3=S4[3], r4=S4[4];
            float f[20] = {r0.x,r0.y,r0.z,r0.w, r1.x,r1.y,r1.z,r1.w,
                           r2.x,r2.y,r2.z,r2.w, r3.x,r3.y,r3.z,r3.w,
                           r4.x,r4.y,r4.z,r4.w};
            float st0 = slab[5*tid], st1 = slab[5*tid+1280],
                  st2 = slab[5*tid+2560], st3 = slab[5*tid+3840];
            float4 bc = *(const float4*)&br[4*tid];
            float nw[4];
            nw[0] = lse5(fmaf(st0,L2E,bo[0]), fmaf(f[1],L2E,bc.x), fmaf(f[6],L2E,bc.y),
                         fmaf(f[11],L2E,bc.z), fmaf(f[16],L2E,bc.w));
            nw[1] = lse5(fmaf(st1,L2E,bo[1]), fmaf(f[2],L2E,bc.x), fmaf(f[7],L2E,bc.y),
                         fmaf(f[12],L2E,bc.z), fmaf(f[17],L2E,bc.w));
            nw[2] = lse5(fmaf(st2,L2E,bo[2]), fmaf(f[3],L2E,bc.x), fmaf(f[8],L2E,bc.y),
                         fmaf(f[13],L2E,bc.z), fmaf(f[18],L2E,bc.w));
            nw[3] = lse5(fmaf(st3,L2E,bo[3]), fmaf(f[4],L2E,bc.x), fmaf(f[9],L2E,bc.y),
                         fmaf(f[14],L2E,bc.z), fmaf(f[19],L2E,bc.w));
            bo[0]=nw[0]; bo[1]=nw[1]; bo[2]=nw[2]; bo[3]=nw[3];
            bw[tid] = nw[0]; bw[tid+256] = nw[1]; bw[tid+512] = nw[2]; bw[tid+768] = nw[3];
            float* tp_ = br; br = bw; bw = tp_;
            ++pp;
        }
    }
    ws[WS_BT + b*RS + tid]       = bo[0];
    ws[WS_BT + b*RS + tid + 256] = bo[1];
    ws[WS_BT + b*RS + tid + 512] = bo[2];
    ws[WS_BT + b*RS + tid + 768] = bo[3];
}

// ===================== banded CTC =====================
__device__ __forceinline__ void ldc(const float* __restrict__ p,
                                    const int (&so)[7], const int (&mo)[7],
                                    float (&S)[7], float (&V)[7]) {
#pragma unroll
    for (int k = 0; k < 7; ++k) { S[k] = p[so[k]]; V[k] = p[mo[k]]; }
}

__device__ __forceinline__ void cstep(const float (&S)[7], const float (&V)[7],
                                      float (&ac)[7], int lane) {
    float prev = __shfl_up(ac[6], 1, 64);
    float nw[7];
#pragma unroll
    for (int k = 0; k < 7; ++k) {
        float left = k ? ac[k-1] : prev;
        float x = fmaf(S[k], L2E, ac[k]);
        float y = fmaf(V[k], L2E, left);
        if (k == 0) y = (lane == 0) ? NEGF : y;
        float m2 = fmaxf(x, y);
        float d  = fminf(x, y) - m2;
        nw[k] = m2 + log2f(1.0f + exp2f(d));
    }
#pragma unroll
    for (int k = 0; k < 7; ++k) ac[k] = nw[k];
}

__device__ __forceinline__ void cstep_b(const float (&S)[7], const float (&V)[7],
                                        float (&ac)[7], int lane) {
    float nxt = __shfl_down(ac[0], 1, 64);
    float nw[7];
#pragma unroll
    for (int k = 0; k < 7; ++k) {
        int gi = 7*lane + k;
        float bn = (k < 6) ? ac[k+1] : nxt;
        float x = fmaf(S[k], L2E, ac[k]);
        float y = fmaf(V[k], L2E, bn);
        y = (gi < NC-1) ? y : NEGF;
        float m2 = fmaxf(x, y);
        float d  = fminf(x, y) - m2;
        float r  = m2 + log2f(1.0f + exp2f(d));
        nw[k] = (gi < NC) ? r : NEGF;
    }
#pragma unroll
    for (int k = 0; k < 7; ++k) ac[k] = nw[k];
}

__device__ void build_tloc(const int* __restrict__ targets, int b, int lane, int (&tloc)[12]) {
#pragma unroll
    for (int j = 0; j < 12; ++j) {
        int gi = 7*lane - 1 + j;
        gi = gi < 0 ? 0 : (gi > LT-1 ? LT-1 : gi);
        int v = targets[b*LT + gi] - 1;
        tloc[j] = v < 0 ? 0 : v;
    }
}

__device__ void ctc_fwd(const float* __restrict__ scores, const int* __restrict__ targets,
                        float* __restrict__ ws, int b, int lane) {
    int tloc[12]; build_tloc(targets, b, lane, tloc);
    int so[7], mo[7];
#pragma unroll
    for (int k = 0; k < 7; ++k) {
        int gi = 7*lane + k;
        if (gi < NC) {
            int K = tloc[k+1];
            K = K*4 + tloc[k+2]; K = K*4 + tloc[k+3];
            K = K*4 + tloc[k+4]; K = K*4 + tloc[k+5];
            so[k] = K*5;
            mo[k] = (gi >= 1) ? (so[k] + tloc[k] + 1) : 0;
        } else { so[k] = 0; mo[k] = 0; }
    }
    float ac[7];
#pragma unroll
    for (int k = 0; k < 7; ++k) ac[k] = (7*lane + k == 0) ? 0.f : NEGF;

    const size_t STP = (size_t)NB*CD;
    const float* q0 = scores + (size_t)b*CD;
    const float* q1 = q0 + STP; const float* q2 = q0 + 2*STP; const float* q3 = q0 + 3*STP;
    float S0[7],V0[7],S1[7],V1[7],S2[7],V2[7],S3[7],V3[7];
    ldc(q0,so,mo,S0,V0); ldc(q1,so,mo,S1,V1); ldc(q2,so,mo,S2,V2); ldc(q3,so,mo,S3,V3);
    for (int t = 0; t < HT-2; t += 4) {
        cstep(S0,V0,ac,lane); if (t+4 < HT) { q0 += 4*STP; ldc(q0,so,mo,S0,V0); }
        cstep(S1,V1,ac,lane); if (t+5 < HT) { q1 += 4*STP; ldc(q1,so,mo,S1,V1); }
        cstep(S2,V2,ac,lane); if (t+6 < HT) { q2 += 4*STP; ldc(q2,so,mo,S2,V2); }
        cstep(S3,V3,ac,lane); if (t+7 < HT) { q3 += 4*STP; ldc(q3,so,mo,S3,V3); }
    }
    cstep(S0,V0,ac,lane);   // t = 248
    cstep(S1,V1,ac,lane);   // t = 249
#pragma unroll
    for (int k = 0; k < 7; ++k) {
        int gi = 7*lane + k;
        if (gi < NC) ws[WS_AC + b*NC + gi] = ac[k];
    }
}

__device__ void ctc_bwd(const float* __restrict__ scores, const int* __restrict__ targets,
                        const int* __restrict__ tlens, float* __restrict__ ws, int b, int lane) {
    int tloc[12]; build_tloc(targets, b, lane, tloc);
    int so[7], vo[7];
#pragma unroll
    for (int k = 0; k < 7; ++k) {
        int gi = 7*lane + k;
        if (gi < NC) {
            int K = tloc[k+1];
            K = K*4 + tloc[k+2]; K = K*4 + tloc[k+3];
            K = K*4 + tloc[k+4]; K = K*4 + tloc[k+5];
            so[k] = K*5;
            if (gi < NC-1) {
                int K2 = tloc[k+2];
                K2 = K2*4 + tloc[k+3]; K2 = K2*4 + tloc[k+4];
                K2 = K2*4 + tloc[k+5]; K2 = K2*4 + tloc[k+6];
                vo[k] = K2*5 + tloc[k+1] + 1;   // move weight out of state gi
            } else vo[k] = 0;
        } else { so[k] = 0; vo[k] = 0; }
    }
    int tl = tlens[b];
    float ac[7];
#pragma unroll
    for (int k = 0; k < 7; ++k) ac[k] = (7*lane + k == tl-5) ? 0.f : NEGF;

    const size_t STP = (size_t)NB*CD;
    const float* q0 = scores + ((size_t)(TT-1)*NB + b)*CD;
    const float* q1 = q0 - STP; const float* q2 = q0 - 2*STP; const float* q3 = q0 - 3*STP;
    float S0[7],V0[7],S1[7],V1[7],S2[7],V2[7],S3[7],V3[7];
    ldc(q0,so,vo,S0,V0); ldc(q1,so,vo,S1,V1); ldc(q2,so,vo,S2,V2); ldc(q3,so,vo,S3,V3);
    for (int p = 0; p < HT-2; p += 4) {
        cstep_b(S0,V0,ac,lane); if (p+4 < HT) { q0 -= 4*STP; ldc(q0,so,vo,S0,V0); }
        cstep_b(S1,V1,ac,lane); if (p+5 < HT) { q1 -= 4*STP; ldc(q1,so,vo,S1,V1); }
        cstep_b(S2,V2,ac,lane); if (p+6 < HT) { q2 -= 4*STP; ldc(q2,so,vo,S2,V2); }
        cstep_b(S3,V3,ac,lane); if (p+7 < HT) { q3 -= 4*STP; ldc(q3,so,vo,S3,V3); }
    }
    cstep_b(S0,V0,ac,lane);   // t = 251
    cstep_b(S1,V1,ac,lane);   // t = 250
#pragma unroll
    for (int k = 0; k < 7; ++k) {
        int gi = 7*lane + k;
        if (gi < NC) ws[WS_BC + b*NC + gi] = ac[k];
    }
}

// ===================== kernels =====================
extern "C" __global__ void __launch_bounds__(256, 1)
ctc_crf_main(const float* __restrict__ scores, const int* __restrict__ targets,
             const int* __restrict__ tlens, float* __restrict__ ws)
{
    extern __shared__ float sm[];
    const int blk = blockIdx.x, tid = threadIdx.x;
    if (blk < NB)            trellis_fwd(scores, ws, blk, tid, sm);
    else if (blk < 2*NB)     trellis_bwd(scores, ws, blk - NB, tid, sm);
    else if (blk < 3*NB)     { if (tid < 64) ctc_fwd(scores, targets, ws, blk - 2*NB, tid); }
    else                     { if (tid < 64) ctc_bwd(scores, targets, tlens, ws, blk - 3*NB, tid); }
}

extern "C" __global__ void __launch_bounds__(256, 1)
ctc_crf_combine(const float* __restrict__ ws, const int* __restrict__ tlens,
                float* __restrict__ out)
{
    const int b = blockIdx.x, tid = threadIdx.x, lane = tid & 63, w = tid >> 6;
    __shared__ float r1[4], r2[4];

    float4 a4 = *(const float4*)&ws[WS_AT + b*RS + 4*tid];
    float4 b4 = *(const float4*)&ws[WS_BT + b*RS + 4*tid];
    float v0 = a4.x+b4.x, v1 = a4.y+b4.y, v2 = a4.z+b4.z, v3 = a4.w+b4.w;
    float m = fmaxf(fmaxf(v0,v1), fmaxf(v2,v3));
#pragma unroll
    for (int o = 32; o >= 1; o >>= 1) m = fmaxf(m, __shfl_xor(m, o, 64));
    if (lane == 0) r1[w] = m;
    __syncthreads();
    float g = fmaxf(fmaxf(r1[0],r1[1]), fmaxf(r1[2],r1[3]));
    float e = exp2f(v0-g)+exp2f(v1-g)+exp2f(v2-g)+exp2f(v3-g);
#pragma unroll
    for (int o = 32; o >= 1; o >>= 1) e += __shfl_xor(e, o, 64);
    if (lane == 0) r2[w] = e;
    __syncthreads();
    float zfull = g + log2f(r2[0]+r2[1]+r2[2]+r2[3]);
    __syncthreads();   // r1/r2 reused below

    float c0 = (tid < NC)     ? ws[WS_AC + b*NC + tid]       + ws[WS_BC + b*NC + tid]       : NEGF;
    float c1 = (tid+256 < NC) ? ws[WS_AC + b*NC + tid + 256] + ws[WS_BC + b*NC + tid + 256] : NEGF;
    float mc = fmaxf(c0, c1);
#pragma unroll
    for (int o = 32; o >= 1; o >>= 1) mc = fmaxf(mc, __shfl_xor(mc, o, 64));
    if (lane == 0) r1[w] = mc;
    __syncthreads();
    float gc = fmaxf(fmaxf(r1[0],r1[1]), fmaxf(r1[2],r1[3]));
    float ec = exp2f(c0-gc)+exp2f(c1-gc);
#pragma unroll
    for (int o = 32; o >= 1; o >>= 1) ec += __shfl_xor(ec, o, 64);
    if (lane == 0) r2[w] = ec;
    __syncthreads();
    if (tid == 0) {
        float zctc = gc + log2f(r2[0]+r2[1]+r2[2]+r2[3]);
        int tl = tlens[b];
        float loss_b = LN2f * (zfull - zctc) / (float)tl;
        atomicAdd(out, loss_b / (float)NB);
    }
}

extern "C" void kernel_launch(void* const* d_in, const int* in_sizes, int n_in,
                              void* d_out, int out_size, void* d_ws, size_t ws_size,
                              hipStream_t stream) {
    const float* scores  = (const float*)d_in[0];
    const int*   targets = (const int*)d_in[1];
    const int*   tlens   = (const int*)d_in[2];
    float* out = (float*)d_out;
    float* ws  = (float*)d_ws;

    hipFuncSetAttribute((const void*)ctc_crf_main,
                        hipFuncAttributeMaxDynamicSharedMemorySize, SMEM_BYTES);
    hipMemsetAsync(out, 0, sizeof(float), stream);
    ctc_crf_main<<<4*NB, 256, SMEM_BYTES, stream>>>(scores, targets, tlens, ws);
    ctc_crf_combine<<<NB, 256, 0, stream>>>(ws, tlens, out);
}